// Round 2
// baseline (612.927 us; speedup 1.0000x reference)
//
#include <hip/hip_runtime.h>
#include <hip/hip_bf16.h>
#include <stdint.h>

// ---------------------------------------------------------------------------
// MHA forward, B=2 S=2048 E=1024 H=16 D=64, fp32 in/out, bf16 MFMA internally.
// cvt(f32->bf16) -> pack mask -> QKV proj GEMM (z=3) -> V transpose ->
// flash attention (swapped QK^T, exp2-space online softmax, reg-prefetch) ->
// out proj.
// ---------------------------------------------------------------------------

typedef __bf16 bf16x8 __attribute__((ext_vector_type(8)));
typedef __bf16 bf16x4 __attribute__((ext_vector_type(4)));
typedef float  f32x4  __attribute__((ext_vector_type(4)));
typedef unsigned int u32x4 __attribute__((ext_vector_type(4)));

#define MFMA16(a, b, c) __builtin_amdgcn_mfma_f32_16x16x32_bf16((a), (b), (c), 0, 0, 0)

static constexpr int kB = 2, kS = 2048, kE = 1024, kH = 16, kD = 64;
static constexpr int kM = kB * kS;                // 4096 rows
static constexpr int kMaskWordsPerRow = kS / 64;  // 32
static constexpr float kLog2e = 1.4426950408889634f;

// ---- async global->LDS (16B per lane, wave-uniform LDS base) --------------
__device__ __forceinline__ void gload_lds16(const void* g, void* l) {
  __builtin_amdgcn_global_load_lds(
      (const __attribute__((address_space(1))) unsigned int*)g,
      (__attribute__((address_space(3))) unsigned int*)l, 16, 0, 0);
}

__device__ __forceinline__ unsigned pack_bf16x2(float a, float b) {
  unsigned short lo = __builtin_bit_cast(unsigned short, (__bf16)a);
  unsigned short hi = __builtin_bit_cast(unsigned short, (__bf16)b);
  return (unsigned)lo | ((unsigned)hi << 16);
}

// ---------------------------------------------------------------------------
// Kernel 1: f32 -> bf16 conversion for q,k,v,Wq,Wk,Wv,Wo
// ---------------------------------------------------------------------------
__global__ __launch_bounds__(256) void cvt_kernel(
    const float* __restrict__ q, const float* __restrict__ k, const float* __restrict__ v,
    const float* __restrict__ wq, const float* __restrict__ wk,
    const float* __restrict__ wv, const float* __restrict__ wo,
    __bf16* __restrict__ qb, __bf16* __restrict__ kb, __bf16* __restrict__ vb,
    __bf16* __restrict__ wqb, __bf16* __restrict__ wkb,
    __bf16* __restrict__ wvb, __bf16* __restrict__ wob) {
  const int z = blockIdx.y;
  const float* src; __bf16* dst; int n;
  switch (z) {
    case 0: src = q;  dst = qb;  n = kM * kE; break;
    case 1: src = k;  dst = kb;  n = kM * kE; break;
    case 2: src = v;  dst = vb;  n = kM * kE; break;
    case 3: src = wq; dst = wqb; n = kE * kE; break;
    case 4: src = wk; dst = wkb; n = kE * kE; break;
    case 5: src = wv; dst = wvb; n = kE * kE; break;
    default: src = wo; dst = wob; n = kE * kE; break;
  }
  const int n4 = n >> 2;
  const int stride = gridDim.x * blockDim.x;
  for (int i = blockIdx.x * blockDim.x + threadIdx.x; i < n4; i += stride) {
    float4 f = ((const float4*)src)[i];
    bf16x4 o = {(__bf16)f.x, (__bf16)f.y, (__bf16)f.z, (__bf16)f.w};
    ((bf16x4*)dst)[i] = o;
  }
}

// ---------------------------------------------------------------------------
// Kernel 2: mask int32 [B,S,S] -> u64 bitmask [B,S,S/64] via wave ballot
// ---------------------------------------------------------------------------
__global__ __launch_bounds__(256) void pack_mask_kernel(
    const int* __restrict__ mask, unsigned long long* __restrict__ mw) {
  const int lane = threadIdx.x & 63;
  const int wid = (blockIdx.x * blockDim.x + threadIdx.x) >> 6;
  const int nwaves = (gridDim.x * blockDim.x) >> 6;
  const int nwords = kB * kS * kMaskWordsPerRow;  // 131072
  for (int w = wid; w < nwords; w += nwaves) {
    int v = mask[(size_t)w * 64 + lane];
    unsigned long long bits = __ballot(v != 0);
    if (lane == 0) mw[w] = bits;
  }
}

// ---------------------------------------------------------------------------
// Kernel 3/6: C = A[4096,1024] @ W^T[1024,1024] + bias   (NT, bf16 MFMA)
// mode 0: -> Qh [B,H,S,D] bf16, scaled by (1/8)*log2e
// mode 1: -> Kh [B,H,S,D] bf16
// mode 2: -> Vh [B,H,S,D] bf16
// mode 3: -> OF f32 [4096,1024]
// ---------------------------------------------------------------------------
__global__ __launch_bounds__(256) void gemm_bt(
    const __bf16* __restrict__ A0, const __bf16* __restrict__ A1, const __bf16* __restrict__ A2,
    const __bf16* __restrict__ W0, const __bf16* __restrict__ W1, const __bf16* __restrict__ W2,
    const float* __restrict__ b0, const float* __restrict__ b1, const float* __restrict__ b2,
    __bf16* __restrict__ O0, __bf16* __restrict__ O1, __bf16* __restrict__ O2,
    float* __restrict__ OF, int mode_base) {
  const int z = blockIdx.z;
  const int mode = mode_base + z;
  const __bf16* A = (z == 0) ? A0 : (z == 1) ? A1 : A2;
  const __bf16* W = (z == 0) ? W0 : (z == 1) ? W1 : W2;
  const float* bias = (z == 0) ? b0 : (z == 1) ? b1 : b2;
  __bf16* OutB = (z == 0) ? O0 : (z == 1) ? O1 : O2;
  const float scale = (mode == 0) ? 0.125f * kLog2e : 1.0f;

  const int n0 = blockIdx.x * 128;
  const int m0 = blockIdx.y * 128;
  const int tid = threadIdx.x;
  const int wave = tid >> 6, lane = tid & 63;
  const int g = lane >> 4, qi = lane & 15;
  const int wm = wave >> 1, wn = wave & 1;

  __shared__ __align__(16) __bf16 As[128 * 32];
  __shared__ __align__(16) __bf16 Bs[128 * 32];

  f32x4 acc[4][4];
#pragma unroll
  for (int i = 0; i < 4; ++i)
#pragma unroll
    for (int j = 0; j < 4; ++j) acc[i][j] = (f32x4){0.f, 0.f, 0.f, 0.f};

  for (int k0 = 0; k0 < kE; k0 += 32) {
#pragma unroll
    for (int j = 0; j < 2; ++j) {
      const int c = j * 256 + tid;
      const int r = c >> 2, sl = c & 3;
      const int ldsbase = (j * 256 + wave * 64) * 8;
      gload_lds16(&A[(size_t)(m0 + r) * kE + k0 + sl * 8], &As[ldsbase]);
      gload_lds16(&W[(size_t)(n0 + r) * kE + k0 + sl * 8], &Bs[ldsbase]);
    }
    __syncthreads();

    bf16x8 af[4], bfr[4];
#pragma unroll
    for (int mi = 0; mi < 4; ++mi)
      af[mi] = *(const bf16x8*)&As[(wm * 64 + mi * 16 + qi) * 32 + g * 8];
#pragma unroll
    for (int nj = 0; nj < 4; ++nj)
      bfr[nj] = *(const bf16x8*)&Bs[(wn * 64 + nj * 16 + qi) * 32 + g * 8];
#pragma unroll
    for (int mi = 0; mi < 4; ++mi)
#pragma unroll
      for (int nj = 0; nj < 4; ++nj)
        acc[mi][nj] = MFMA16(af[mi], bfr[nj], acc[mi][nj]);
    __syncthreads();
  }

#pragma unroll
  for (int nj = 0; nj < 4; ++nj) {
    const int ncol = n0 + wn * 64 + nj * 16 + qi;
    const float bn = bias[ncol];
    const int hh = ncol >> 6, dd = ncol & 63;
#pragma unroll
    for (int mi = 0; mi < 4; ++mi) {
#pragma unroll
      for (int r = 0; r < 4; ++r) {
        const int mrow = m0 + wm * 64 + mi * 16 + g * 4 + r;
        const float vv = (acc[mi][nj][r] + bn) * scale;
        if (mode <= 2) {
          const int bb = mrow >> 11, ss = mrow & 2047;
          OutB[((((size_t)bb * kH + hh) * kS + ss) << 6) + dd] = (__bf16)vv;
        } else {
          OF[(size_t)mrow * kE + ncol] = vv;
        }
      }
    }
  }
}

// ---------------------------------------------------------------------------
// Kernel 4: per-head transpose Vh [B,H,S,D] -> Vt [B,H,D,S] via LDS tiles
// ---------------------------------------------------------------------------
__global__ __launch_bounds__(256) void transpose_v_kernel(
    const __bf16* __restrict__ Vh, __bf16* __restrict__ Vt) {
  __shared__ __bf16 tile[64][72];
  const int bh = blockIdx.y;
  const int s0 = blockIdx.x * 64;
  const int tid = threadIdx.x;
  const int r16 = tid >> 4;          // 0..15
  const int c4 = (tid & 15) * 4;     // 0..60 step 4
  const __bf16* src = Vh + (size_t)bh * kS * kD;
#pragma unroll
  for (int rr = 0; rr < 4; ++rr) {
    const int srow = rr * 16 + r16;
    ushort4 u = *(const ushort4*)&src[(size_t)(s0 + srow) * kD + c4];
    *(ushort4*)&tile[srow][c4] = u;
  }
  __syncthreads();
  __bf16* dst = Vt + (size_t)bh * kD * kS;
#pragma unroll
  for (int rr = 0; rr < 4; ++rr) {
    const int d = rr * 16 + r16;
    ushort4 o;
    o.x = __builtin_bit_cast(unsigned short, tile[c4 + 0][d]);
    o.y = __builtin_bit_cast(unsigned short, tile[c4 + 1][d]);
    o.z = __builtin_bit_cast(unsigned short, tile[c4 + 2][d]);
    o.w = __builtin_bit_cast(unsigned short, tile[c4 + 3][d]);
    *(ushort4*)&dst[(size_t)d * kS + s0 + c4] = o;
  }
}

// ---------------------------------------------------------------------------
// Kernel 5: flash attention, swapped QK^T, exp2-space online softmax,
// register-rotation prefetch of K/V/mask, XCD-swizzled grid.
// ---------------------------------------------------------------------------
__global__ __launch_bounds__(256, 4) void attn_kernel(
    const __bf16* __restrict__ Qh, const __bf16* __restrict__ Kh,
    const __bf16* __restrict__ Vt, const unsigned long long* __restrict__ mw,
    __bf16* __restrict__ Ob) {
  const int wave = threadIdx.x >> 6, lane = threadIdx.x & 63;
  const int g = lane >> 4, qi = lane & 15;
  // XCD swizzle: 1024 blocks; id%8 = XCD; 4 heads per XCD -> K/V L2-resident.
  const int id = blockIdx.x;
  const int bh = (id & 7) * 4 + (id >> 8);   // 0..31
  const int qb = (id >> 3) & 31;             // 0..31
  const int b = bh >> 4, h = bh & 15;
  const int q = qb * 64 + wave * 16 + qi;

  const __bf16* Qp = Qh + (size_t)bh * kS * kD;
  const __bf16* Kp = Kh + (size_t)bh * kS * kD;
  const __bf16* Vp = Vt + (size_t)bh * kD * kS;
  const unsigned long long* mrow = mw + (size_t)(b * kS + q) * kMaskWordsPerRow;

  // Q fragments (B-operand); (1/8)*log2e pre-folded into Qh.
  bf16x8 qf0 = *(const bf16x8*)&Qp[(size_t)q * kD + g * 8];
  bf16x8 qf1 = *(const bf16x8*)&Qp[(size_t)q * kD + 32 + g * 8];

  f32x4 acc[4];  // out^T: rows d = f*16+g*4+r, col q
#pragma unroll
  for (int f = 0; f < 4; ++f) acc[f] = (f32x4){0.f, 0.f, 0.f, 0.f};
  float mrun = -3.0e38f, den = 0.f;

  // prefetch tile 0
  bf16x8 kf[8], vf[8];
#pragma unroll
  for (int f = 0; f < 4; ++f) {
    const __bf16* kr = &Kp[(size_t)(f * 16 + qi) * kD];
    kf[2 * f]     = *(const bf16x8*)&kr[g * 8];
    kf[2 * f + 1] = *(const bf16x8*)&kr[32 + g * 8];
  }
#pragma unroll
  for (int c = 0; c < 2; ++c)
#pragma unroll
    for (int f = 0; f < 4; ++f)
      vf[4 * c + f] = *(const bf16x8*)&Vp[(size_t)(f * 16 + qi) * kS + c * 32 + g * 8];
  unsigned long long w = mrow[0];

  for (int kv0 = 0; kv0 < kS; kv0 += 64) {
    const int kvn = (kv0 + 64) & (kS - 1);  // wraps to 0 on last iter (discarded)
    // ---- QK^T (swapped) + mask ----
    float s[16];
#pragma unroll
    for (int f = 0; f < 4; ++f) {
      f32x4 st = (f32x4){0.f, 0.f, 0.f, 0.f};
      st = MFMA16(kf[2 * f], qf0, st);
      st = MFMA16(kf[2 * f + 1], qf1, st);
#pragma unroll
      for (int r = 0; r < 4; ++r)
        s[4 * f + r] = ((w >> (f * 16 + g * 4 + r)) & 1ull) ? st[r] : -1.0e9f;
    }
    // ---- prefetch K(t+1), mask(t+1): latency hides under softmax+PV ----
#pragma unroll
    for (int f = 0; f < 4; ++f) {
      const __bf16* kr = &Kp[(size_t)(kvn + f * 16 + qi) * kD];
      kf[2 * f]     = *(const bf16x8*)&kr[g * 8];
      kf[2 * f + 1] = *(const bf16x8*)&kr[32 + g * 8];
    }
    w = mrow[kvn >> 6];
    // ---- online softmax in exp2 space, defer-max (THR=8) ----
    float tm = s[0];
#pragma unroll
    for (int i = 1; i < 16; ++i) tm = fmaxf(tm, s[i]);
    tm = fmaxf(tm, __shfl_xor(tm, 16));
    tm = fmaxf(tm, __shfl_xor(tm, 32));
    if (!__all(tm <= mrun + 8.0f)) {
      const float mn = fmaxf(mrun, tm);
      const float al = exp2f(mrun - mn);
      den *= al;
#pragma unroll
      for (int f = 0; f < 4; ++f) acc[f] *= al;
      mrun = mn;
    }
    float tsum = 0.f;
#pragma unroll
    for (int i = 0; i < 16; ++i) {
      s[i] = exp2f(s[i] - mrun);
      tsum += s[i];
    }
    tsum += __shfl_xor(tsum, 16);
    tsum += __shfl_xor(tsum, 32);
    den += tsum;
    // ---- P (st-layout) -> bf16 PV b-fragments via cross-lane shuffle ----
    unsigned pk[4][2];
#pragma unroll
    for (int f = 0; f < 4; ++f) {
      pk[f][0] = pack_bf16x2(s[f * 4 + 0], s[f * 4 + 1]);
      pk[f][1] = pack_bf16x2(s[f * 4 + 2], s[f * 4 + 3]);
    }
#pragma unroll
    for (int c = 0; c < 2; ++c) {
      unsigned bw[4];
#pragma unroll
      for (int t = 0; t < 4; ++t) {
        const int src = qi + 16 * ((t >> 1) + 2 * (g & 1));
        const int vA = __shfl((int)pk[2 * c + 0][t & 1], src);
        const int vB = __shfl((int)pk[2 * c + 1][t & 1], src);
        bw[t] = (g >= 2) ? (unsigned)vB : (unsigned)vA;
      }
      u32x4 tmp = {bw[0], bw[1], bw[2], bw[3]};
      const bf16x8 pb = __builtin_bit_cast(bf16x8, tmp);
#pragma unroll
      for (int f = 0; f < 4; ++f)
        acc[f] = MFMA16(vf[4 * c + f], pb, acc[f]);
    }
    // ---- prefetch V(t+1): latency hides under next QK+softmax ----
#pragma unroll
    for (int c2 = 0; c2 < 2; ++c2)
#pragma unroll
      for (int f = 0; f < 4; ++f)
        vf[4 * c2 + f] =
            *(const bf16x8*)&Vp[(size_t)(f * 16 + qi) * kS + kvn + c2 * 32 + g * 8];
  }

  const float rinv = 1.0f / den;
  __bf16* Op = Ob + (size_t)(b * kS + q) * kE + h * kD;
#pragma unroll
  for (int f = 0; f < 4; ++f) {
    ushort4 o;
    o.x = __builtin_bit_cast(unsigned short, (__bf16)(acc[f][0] * rinv));
    o.y = __builtin_bit_cast(unsigned short, (__bf16)(acc[f][1] * rinv));
    o.z = __builtin_bit_cast(unsigned short, (__bf16)(acc[f][2] * rinv));
    o.w = __builtin_bit_cast(unsigned short, (__bf16)(acc[f][3] * rinv));
    *(ushort4*)&Op[f * 16 + g * 4] = o;
  }
}

// ---------------------------------------------------------------------------
extern "C" void kernel_launch(void* const* d_in, const int* in_sizes, int n_in,
                              void* d_out, int out_size, void* d_ws, size_t ws_size,
                              hipStream_t stream) {
  (void)in_sizes; (void)n_in; (void)out_size; (void)ws_size;
  const float* q  = (const float*)d_in[0];
  const float* k  = (const float*)d_in[1];
  const float* v  = (const float*)d_in[2];
  const int*   mask = (const int*)d_in[3];
  const float* Wq = (const float*)d_in[4];
  const float* bq = (const float*)d_in[5];
  const float* Wk = (const float*)d_in[6];
  const float* bk = (const float*)d_in[7];
  const float* Wv = (const float*)d_in[8];
  const float* bv = (const float*)d_in[9];
  const float* Wo = (const float*)d_in[10];
  const float* bo = (const float*)d_in[11];

  char* ws = (char*)d_ws;
  const size_t MB = 1024 * 1024;
  __bf16* qb  = (__bf16*)(ws + 0 * MB);    // 8MB  [4096,1024]
  __bf16* kb  = (__bf16*)(ws + 8 * MB);    // 8MB  (dead after GEMM -> reused as Vt)
  __bf16* vb  = (__bf16*)(ws + 16 * MB);   // 8MB
  __bf16* wqb = (__bf16*)(ws + 24 * MB);   // 2MB
  __bf16* wkb = (__bf16*)(ws + 26 * MB);   // 2MB
  __bf16* wvb = (__bf16*)(ws + 28 * MB);   // 2MB
  __bf16* wob = (__bf16*)(ws + 30 * MB);   // 2MB
  __bf16* Qh  = (__bf16*)(ws + 32 * MB);   // 8MB [B,H,S,D]
  __bf16* Kh  = (__bf16*)(ws + 40 * MB);   // 8MB [B,H,S,D]
  __bf16* Vh  = (__bf16*)(ws + 48 * MB);   // 8MB [B,H,S,D]
  unsigned long long* mwords = (unsigned long long*)(ws + 56 * MB);  // 1MB
  __bf16* Vt = kb;   // kb dead after QKV GEMM
  __bf16* Ob = qb;   // qb dead after QKV GEMM

  cvt_kernel<<<dim3(256, 7), 256, 0, stream>>>(q, k, v, Wq, Wk, Wv, Wo,
                                               qb, kb, vb, wqb, wkb, wvb, wob);
  pack_mask_kernel<<<256, 256, 0, stream>>>(mask, mwords);
  gemm_bt<<<dim3(8, 32, 3), 256, 0, stream>>>(qb, kb, vb, wqb, wkb, wvb,
                                              bq, bk, bv, Qh, Kh, Vh, nullptr, 0);
  transpose_v_kernel<<<dim3(32, 32), 256, 0, stream>>>(Vh, Vt);
  attn_kernel<<<1024, 256, 0, stream>>>(Qh, Kh, Vt, mwords, Ob);
  gemm_bt<<<dim3(8, 32, 1), 256, 0, stream>>>(Ob, Ob, Ob, wob, wob, wob,
                                              bo, bo, bo, nullptr, nullptr, nullptr,
                                              (float*)d_out, 3);
}

// Round 3
// 321.596 us; speedup vs baseline: 1.9059x; 1.9059x over previous
//
#include <hip/hip_runtime.h>
#include <hip/hip_bf16.h>
#include <stdint.h>

// ---------------------------------------------------------------------------
// MHA forward, B=2 S=2048 E=1024 H=16 D=64, fp32 in/out, bf16 MFMA internally.
// cvt(f32->bf16) -> pack mask -> QKV proj GEMM (z=3) -> V transpose ->
// flash attention (LDS double-buffered K/V, XOR-swizzled, swapped QK^T,
// exp2 online softmax) -> out proj (128x64 tiles).
// ---------------------------------------------------------------------------

typedef __bf16 bf16x8 __attribute__((ext_vector_type(8)));
typedef __bf16 bf16x4 __attribute__((ext_vector_type(4)));
typedef float  f32x4  __attribute__((ext_vector_type(4)));
typedef unsigned int u32x4 __attribute__((ext_vector_type(4)));

#define MFMA16(a, b, c) __builtin_amdgcn_mfma_f32_16x16x32_bf16((a), (b), (c), 0, 0, 0)

static constexpr int kB = 2, kS = 2048, kE = 1024, kH = 16, kD = 64;
static constexpr int kM = kB * kS;                // 4096 rows
static constexpr int kMaskWordsPerRow = kS / 64;  // 32
static constexpr float kLog2e = 1.4426950408889634f;

// ---- async global->LDS (16B per lane, wave-uniform LDS base) --------------
__device__ __forceinline__ void gload_lds16(const void* g, void* l) {
  __builtin_amdgcn_global_load_lds(
      (const __attribute__((address_space(1))) unsigned int*)g,
      (__attribute__((address_space(3))) unsigned int*)l, 16, 0, 0);
}

__device__ __forceinline__ unsigned pack_bf16x2(float a, float b) {
  unsigned short lo = __builtin_bit_cast(unsigned short, (__bf16)a);
  unsigned short hi = __builtin_bit_cast(unsigned short, (__bf16)b);
  return (unsigned)lo | ((unsigned)hi << 16);
}

// ---------------------------------------------------------------------------
// Kernel 1: f32 -> bf16 conversion for q,k,v,Wq,Wk,Wv,Wo
// ---------------------------------------------------------------------------
__global__ __launch_bounds__(256) void cvt_kernel(
    const float* __restrict__ q, const float* __restrict__ k, const float* __restrict__ v,
    const float* __restrict__ wq, const float* __restrict__ wk,
    const float* __restrict__ wv, const float* __restrict__ wo,
    __bf16* __restrict__ qb, __bf16* __restrict__ kb, __bf16* __restrict__ vb,
    __bf16* __restrict__ wqb, __bf16* __restrict__ wkb,
    __bf16* __restrict__ wvb, __bf16* __restrict__ wob) {
  const int z = blockIdx.y;
  const float* src; __bf16* dst; int n;
  switch (z) {
    case 0: src = q;  dst = qb;  n = kM * kE; break;
    case 1: src = k;  dst = kb;  n = kM * kE; break;
    case 2: src = v;  dst = vb;  n = kM * kE; break;
    case 3: src = wq; dst = wqb; n = kE * kE; break;
    case 4: src = wk; dst = wkb; n = kE * kE; break;
    case 5: src = wv; dst = wvb; n = kE * kE; break;
    default: src = wo; dst = wob; n = kE * kE; break;
  }
  const int n4 = n >> 2;
  const int stride = gridDim.x * blockDim.x;
  for (int i = blockIdx.x * blockDim.x + threadIdx.x; i < n4; i += stride) {
    float4 f = ((const float4*)src)[i];
    bf16x4 o = {(__bf16)f.x, (__bf16)f.y, (__bf16)f.z, (__bf16)f.w};
    ((bf16x4*)dst)[i] = o;
  }
}

// ---------------------------------------------------------------------------
// Kernel 2: mask int32 [B,S,S] -> u64 bitmask [B,S,S/64] via wave ballot
// ---------------------------------------------------------------------------
__global__ __launch_bounds__(256) void pack_mask_kernel(
    const int* __restrict__ mask, unsigned long long* __restrict__ mw) {
  const int lane = threadIdx.x & 63;
  const int wid = (blockIdx.x * blockDim.x + threadIdx.x) >> 6;
  const int nwaves = (gridDim.x * blockDim.x) >> 6;
  const int nwords = kB * kS * kMaskWordsPerRow;  // 131072
  for (int w = wid; w < nwords; w += nwaves) {
    int v = mask[(size_t)w * 64 + lane];
    unsigned long long bits = __ballot(v != 0);
    if (lane == 0) mw[w] = bits;
  }
}

// ---------------------------------------------------------------------------
// Kernel 3: C = A[4096,1024] @ W^T + bias (NT, bf16 MFMA), 128x128 tile.
// mode 0: -> Qh [B,H,S,D] bf16 scaled by (1/8)*log2e; 1: Kh; 2: Vh.
// ---------------------------------------------------------------------------
__global__ __launch_bounds__(256) void gemm_bt(
    const __bf16* __restrict__ A0, const __bf16* __restrict__ A1, const __bf16* __restrict__ A2,
    const __bf16* __restrict__ W0, const __bf16* __restrict__ W1, const __bf16* __restrict__ W2,
    const float* __restrict__ b0, const float* __restrict__ b1, const float* __restrict__ b2,
    __bf16* __restrict__ O0, __bf16* __restrict__ O1, __bf16* __restrict__ O2) {
  const int z = blockIdx.z;
  const __bf16* A = (z == 0) ? A0 : (z == 1) ? A1 : A2;
  const __bf16* W = (z == 0) ? W0 : (z == 1) ? W1 : W2;
  const float* bias = (z == 0) ? b0 : (z == 1) ? b1 : b2;
  __bf16* OutB = (z == 0) ? O0 : (z == 1) ? O1 : O2;
  const float scale = (z == 0) ? 0.125f * kLog2e : 1.0f;

  const int n0 = blockIdx.x * 128;
  const int m0 = blockIdx.y * 128;
  const int tid = threadIdx.x;
  const int wave = tid >> 6, lane = tid & 63;
  const int g = lane >> 4, qi = lane & 15;
  const int wm = wave >> 1, wn = wave & 1;

  __shared__ __align__(16) __bf16 As[128 * 32];
  __shared__ __align__(16) __bf16 Bs[128 * 32];

  f32x4 acc[4][4];
#pragma unroll
  for (int i = 0; i < 4; ++i)
#pragma unroll
    for (int jj = 0; jj < 4; ++jj) acc[i][jj] = (f32x4){0.f, 0.f, 0.f, 0.f};

  for (int k0 = 0; k0 < kE; k0 += 32) {
#pragma unroll
    for (int jj = 0; jj < 2; ++jj) {
      const int c = jj * 256 + tid;
      const int r = c >> 2, sl = c & 3;
      gload_lds16(&A[(size_t)(m0 + r) * kE + k0 + sl * 8], &As[c * 8]);
      gload_lds16(&W[(size_t)(n0 + r) * kE + k0 + sl * 8], &Bs[c * 8]);
    }
    __syncthreads();

    bf16x8 af[4], bfr[4];
#pragma unroll
    for (int mi = 0; mi < 4; ++mi)
      af[mi] = *(const bf16x8*)&As[(wm * 64 + mi * 16 + qi) * 32 + g * 8];
#pragma unroll
    for (int nj = 0; nj < 4; ++nj)
      bfr[nj] = *(const bf16x8*)&Bs[(wn * 64 + nj * 16 + qi) * 32 + g * 8];
#pragma unroll
    for (int mi = 0; mi < 4; ++mi)
#pragma unroll
      for (int nj = 0; nj < 4; ++nj)
        acc[mi][nj] = MFMA16(af[mi], bfr[nj], acc[mi][nj]);
    __syncthreads();
  }

#pragma unroll
  for (int nj = 0; nj < 4; ++nj) {
    const int ncol = n0 + wn * 64 + nj * 16 + qi;
    const float bn = bias[ncol];
    const int hh = ncol >> 6, dd = ncol & 63;
#pragma unroll
    for (int mi = 0; mi < 4; ++mi) {
#pragma unroll
      for (int r = 0; r < 4; ++r) {
        const int mrow = m0 + wm * 64 + mi * 16 + g * 4 + r;
        const float vv = (acc[mi][nj][r] + bn) * scale;
        const int bb = mrow >> 11, ss = mrow & 2047;
        OutB[((((size_t)bb * kH + hh) * kS + ss) << 6) + dd] = (__bf16)vv;
      }
    }
  }
}

// ---------------------------------------------------------------------------
// Kernel 3b: out projection, C = A[4096,1024] @ Wo^T + bo -> f32, 128x64 tile
// (512 blocks = 2/CU; the 128x128 version was 1 block/CU -> latency-starved)
// ---------------------------------------------------------------------------
__global__ __launch_bounds__(256) void gemm_out64(
    const __bf16* __restrict__ A, const __bf16* __restrict__ W,
    const float* __restrict__ bias, float* __restrict__ OF) {
  const int n0 = blockIdx.x * 64;
  const int m0 = blockIdx.y * 128;
  const int tid = threadIdx.x;
  const int wave = tid >> 6, lane = tid & 63;
  const int g = lane >> 4, qi = lane & 15;
  const int wm = wave >> 1, wn = wave & 1;

  __shared__ __align__(16) __bf16 As[128 * 32];
  __shared__ __align__(16) __bf16 Bs[64 * 32];

  f32x4 acc[4][2];
#pragma unroll
  for (int i = 0; i < 4; ++i)
#pragma unroll
    for (int jj = 0; jj < 2; ++jj) acc[i][jj] = (f32x4){0.f, 0.f, 0.f, 0.f};

  for (int k0 = 0; k0 < kE; k0 += 32) {
#pragma unroll
    for (int jj = 0; jj < 2; ++jj) {
      const int c = jj * 256 + tid;
      const int r = c >> 2, sl = c & 3;
      gload_lds16(&A[(size_t)(m0 + r) * kE + k0 + sl * 8], &As[c * 8]);
    }
    {
      const int c = tid;
      const int r = c >> 2, sl = c & 3;
      gload_lds16(&W[(size_t)(n0 + r) * kE + k0 + sl * 8], &Bs[c * 8]);
    }
    __syncthreads();

    bf16x8 af[4], bfr[2];
#pragma unroll
    for (int mi = 0; mi < 4; ++mi)
      af[mi] = *(const bf16x8*)&As[(wm * 64 + mi * 16 + qi) * 32 + g * 8];
#pragma unroll
    for (int nj = 0; nj < 2; ++nj)
      bfr[nj] = *(const bf16x8*)&Bs[(wn * 32 + nj * 16 + qi) * 32 + g * 8];
#pragma unroll
    for (int mi = 0; mi < 4; ++mi)
#pragma unroll
      for (int nj = 0; nj < 2; ++nj)
        acc[mi][nj] = MFMA16(af[mi], bfr[nj], acc[mi][nj]);
    __syncthreads();
  }

#pragma unroll
  for (int nj = 0; nj < 2; ++nj) {
    const int ncol = n0 + wn * 32 + nj * 16 + qi;
    const float bn = bias[ncol];
#pragma unroll
    for (int mi = 0; mi < 4; ++mi)
#pragma unroll
      for (int r = 0; r < 4; ++r) {
        const int mrow = m0 + wm * 64 + mi * 16 + g * 4 + r;
        OF[(size_t)mrow * kE + ncol] = acc[mi][nj][r] + bn;
      }
  }
}

// ---------------------------------------------------------------------------
// Kernel 4: per-head transpose Vh [B,H,S,D] -> Vt [B,H,D,S] via LDS tiles
// ---------------------------------------------------------------------------
__global__ __launch_bounds__(256) void transpose_v_kernel(
    const __bf16* __restrict__ Vh, __bf16* __restrict__ Vt) {
  __shared__ __bf16 tile[64][72];
  const int bh = blockIdx.y;
  const int s0 = blockIdx.x * 64;
  const int tid = threadIdx.x;
  const int r16 = tid >> 4;
  const int c4 = (tid & 15) * 4;
  const __bf16* src = Vh + (size_t)bh * kS * kD;
#pragma unroll
  for (int rr = 0; rr < 4; ++rr) {
    const int srow = rr * 16 + r16;
    ushort4 u = *(const ushort4*)&src[(size_t)(s0 + srow) * kD + c4];
    *(ushort4*)&tile[srow][c4] = u;
  }
  __syncthreads();
  __bf16* dst = Vt + (size_t)bh * kD * kS;
#pragma unroll
  for (int rr = 0; rr < 4; ++rr) {
    const int d = rr * 16 + r16;
    ushort4 o;
    o.x = __builtin_bit_cast(unsigned short, tile[c4 + 0][d]);
    o.y = __builtin_bit_cast(unsigned short, tile[c4 + 1][d]);
    o.z = __builtin_bit_cast(unsigned short, tile[c4 + 2][d]);
    o.w = __builtin_bit_cast(unsigned short, tile[c4 + 3][d]);
    *(ushort4*)&dst[(size_t)d * kS + s0 + c4] = o;
  }
}

// ---------------------------------------------------------------------------
// Kernel 5: flash attention.
// 4 waves/block; wave owns 32 q-rows (2 column-tiles of 16). Block = 128 rows.
// K/V kv-tiles (64x64 bf16) double-buffered in LDS via global_load_lds with
// 16B-slot XOR swizzle: LDS slot s of row r holds global slot s^(r&7)
// (inverse-swizzled SOURCE, linear dest, swizzled READ -> conflict-spread).
// Swapped QK^T (st[kv][q]); exp2-space online softmax with defer-max.
// ---------------------------------------------------------------------------
__global__ __launch_bounds__(256, 2) void attn_kernel(
    const __bf16* __restrict__ Qh, const __bf16* __restrict__ Kh,
    const __bf16* __restrict__ Vt, const unsigned long long* __restrict__ mw,
    __bf16* __restrict__ Ob) {
  const int tid = threadIdx.x;
  const int wave = tid >> 6, lane = tid & 63;
  const int g = lane >> 4, qi = lane & 15;
  // XCD swizzle: 512 blocks; xcd = id%8 owns heads xcd*4..xcd*4+3.
  const int id = blockIdx.x;
  const int xcd = id & 7, j = id >> 3;
  const int bh = xcd * 4 + (j >> 4);
  const int qb = j & 15;
  const int b = bh >> 4, h = bh & 15;

  __shared__ __align__(16) __bf16 Ks[2][64 * 64];
  __shared__ __align__(16) __bf16 Vs[2][64 * 64];

  const __bf16* Qp = Qh + (size_t)bh * kS * kD;
  const __bf16* Kp = Kh + (size_t)bh * kS * kD;
  const __bf16* Vp = Vt + (size_t)bh * kD * kS;

  const int q0 = qb * 128 + wave * 32 + qi;  // q-tile 0 row
  const int q1 = q0 + 16;                    // q-tile 1 row
  const unsigned long long* M0 = mw + (size_t)(b * kS + q0) * kMaskWordsPerRow;
  const unsigned long long* M1 = mw + (size_t)(b * kS + q1) * kMaskWordsPerRow;

  // Q fragments (B-operand); (1/8)*log2e pre-folded into Qh.
  const bf16x8 qf00 = *(const bf16x8*)&Qp[(size_t)q0 * kD + g * 8];
  const bf16x8 qf01 = *(const bf16x8*)&Qp[(size_t)q0 * kD + 32 + g * 8];
  const bf16x8 qf10 = *(const bf16x8*)&Qp[(size_t)q1 * kD + g * 8];
  const bf16x8 qf11 = *(const bf16x8*)&Qp[(size_t)q1 * kD + 32 + g * 8];

  f32x4 acc0[4], acc1[4];
#pragma unroll
  for (int f = 0; f < 4; ++f) {
    acc0[f] = (f32x4){0.f, 0.f, 0.f, 0.f};
    acc1[f] = (f32x4){0.f, 0.f, 0.f, 0.f};
  }
  float mr0 = -3.0e38f, mr1 = -3.0e38f, den0 = 0.f, den1 = 0.f;

  // stage kv-tile into LDS buffer: K rows kv (64x64), V rows d (64xkv64).
  // chunk c in [0,512): row=c>>3, 16B slot sl=c&7; source slot sl^(row&7).
  auto stage = [&](int buf, int kv0) {
#pragma unroll
    for (int jj = 0; jj < 2; ++jj) {
      const int c = jj * 256 + tid;  // = base + wave*64 + lane (lane-contig)
      const int row = c >> 3, sl = c & 7;
      const int sls = sl ^ (row & 7);
      gload_lds16(&Kp[(size_t)(kv0 + row) * kD + sls * 8], &Ks[buf][c * 8]);
      gload_lds16(&Vp[(size_t)row * kS + kv0 + sls * 8], &Vs[buf][c * 8]);
    }
  };

  stage(0, 0);
  __syncthreads();

  for (int t = 0; t < 32; ++t) {
    const int cur = t & 1;
    if (t < 31) stage(cur ^ 1, (t + 1) * 64);
    const unsigned long long w0 = M0[t];
    const unsigned long long w1 = M1[t];

    // ---- QK^T (swapped): s[kv 16][q] per f-subtile ----
    float s0[16], s1[16];
    __builtin_amdgcn_s_setprio(1);
#pragma unroll
    for (int f = 0; f < 4; ++f) {
      const int r = f * 16 + qi;
      const int sw = qi & 7;
      const bf16x8 k0 = *(const bf16x8*)&Ks[cur][r * 64 + ((g ^ sw) * 8)];
      const bf16x8 k1 = *(const bf16x8*)&Ks[cur][r * 64 + (((4 + g) ^ sw) * 8)];
      f32x4 st0 = (f32x4){0.f, 0.f, 0.f, 0.f};
      st0 = MFMA16(k0, qf00, st0);
      st0 = MFMA16(k1, qf01, st0);
      f32x4 st1 = (f32x4){0.f, 0.f, 0.f, 0.f};
      st1 = MFMA16(k0, qf10, st1);
      st1 = MFMA16(k1, qf11, st1);
#pragma unroll
      for (int r4 = 0; r4 < 4; ++r4) {
        const int bit = f * 16 + g * 4 + r4;
        s0[4 * f + r4] = ((w0 >> bit) & 1ull) ? st0[r4] : -1.0e9f;
        s1[4 * f + r4] = ((w1 >> bit) & 1ull) ? st1[r4] : -1.0e9f;
      }
    }
    __builtin_amdgcn_s_setprio(0);

    // ---- online softmax (exp2 space, defer-max THR=8), per q-tile ----
    {
      float tm = s0[0];
#pragma unroll
      for (int i = 1; i < 16; ++i) tm = fmaxf(tm, s0[i]);
      tm = fmaxf(tm, __shfl_xor(tm, 16));
      tm = fmaxf(tm, __shfl_xor(tm, 32));
      if (!__all(tm <= mr0 + 8.0f)) {
        const float mn = fmaxf(mr0, tm);
        const float al = exp2f(mr0 - mn);
        den0 *= al;
#pragma unroll
        for (int f = 0; f < 4; ++f) acc0[f] *= al;
        mr0 = mn;
      }
      float ts = 0.f;
#pragma unroll
      for (int i = 0; i < 16; ++i) {
        s0[i] = exp2f(s0[i] - mr0);
        ts += s0[i];
      }
      ts += __shfl_xor(ts, 16);
      ts += __shfl_xor(ts, 32);
      den0 += ts;
    }
    {
      float tm = s1[0];
#pragma unroll
      for (int i = 1; i < 16; ++i) tm = fmaxf(tm, s1[i]);
      tm = fmaxf(tm, __shfl_xor(tm, 16));
      tm = fmaxf(tm, __shfl_xor(tm, 32));
      if (!__all(tm <= mr1 + 8.0f)) {
        const float mn = fmaxf(mr1, tm);
        const float al = exp2f(mr1 - mn);
        den1 *= al;
#pragma unroll
        for (int f = 0; f < 4; ++f) acc1[f] *= al;
        mr1 = mn;
      }
      float ts = 0.f;
#pragma unroll
      for (int i = 0; i < 16; ++i) {
        s1[i] = exp2f(s1[i] - mr1);
        ts += s1[i];
      }
      ts += __shfl_xor(ts, 16);
      ts += __shfl_xor(ts, 32);
      den1 += ts;
    }

    // ---- P -> bf16 PV B-fragments via cross-lane shuffle, then PV ----
    unsigned pk0[4][2], pk1[4][2];
#pragma unroll
    for (int f = 0; f < 4; ++f) {
      pk0[f][0] = pack_bf16x2(s0[4 * f + 0], s0[4 * f + 1]);
      pk0[f][1] = pack_bf16x2(s0[4 * f + 2], s0[4 * f + 3]);
      pk1[f][0] = pack_bf16x2(s1[4 * f + 0], s1[4 * f + 1]);
      pk1[f][1] = pack_bf16x2(s1[4 * f + 2], s1[4 * f + 3]);
    }
#pragma unroll
    for (int c = 0; c < 2; ++c) {
      unsigned bw0[4], bw1[4];
#pragma unroll
      for (int t4 = 0; t4 < 4; ++t4) {
        const int src = qi + 16 * ((t4 >> 1) + 2 * (g & 1));
        const int a0 = __shfl((int)pk0[2 * c + 0][t4 & 1], src);
        const int b0v = __shfl((int)pk0[2 * c + 1][t4 & 1], src);
        bw0[t4] = (g >= 2) ? (unsigned)b0v : (unsigned)a0;
        const int a1 = __shfl((int)pk1[2 * c + 0][t4 & 1], src);
        const int b1v = __shfl((int)pk1[2 * c + 1][t4 & 1], src);
        bw1[t4] = (g >= 2) ? (unsigned)b1v : (unsigned)a1;
      }
      const u32x4 t0 = {bw0[0], bw0[1], bw0[2], bw0[3]};
      const u32x4 t1 = {bw1[0], bw1[1], bw1[2], bw1[3]};
      const bf16x8 pb0 = __builtin_bit_cast(bf16x8, t0);
      const bf16x8 pb1 = __builtin_bit_cast(bf16x8, t1);
      __builtin_amdgcn_s_setprio(1);
#pragma unroll
      for (int f = 0; f < 4; ++f) {
        const int r = f * 16 + qi;
        const int sw = qi & 7;
        const bf16x8 vfr =
            *(const bf16x8*)&Vs[cur][r * 64 + (((c * 4 + g) ^ sw) * 8)];
        acc0[f] = MFMA16(vfr, pb0, acc0[f]);
        acc1[f] = MFMA16(vfr, pb1, acc1[f]);
      }
      __builtin_amdgcn_s_setprio(0);
    }
    __syncthreads();
  }

  const float ri0 = 1.0f / den0;
  const float ri1 = 1.0f / den1;
  __bf16* Op0 = Ob + (size_t)(b * kS + q0) * kE + h * kD;
  __bf16* Op1 = Ob + (size_t)(b * kS + q1) * kE + h * kD;
#pragma unroll
  for (int f = 0; f < 4; ++f) {
    ushort4 o0, o1;
    o0.x = __builtin_bit_cast(unsigned short, (__bf16)(acc0[f][0] * ri0));
    o0.y = __builtin_bit_cast(unsigned short, (__bf16)(acc0[f][1] * ri0));
    o0.z = __builtin_bit_cast(unsigned short, (__bf16)(acc0[f][2] * ri0));
    o0.w = __builtin_bit_cast(unsigned short, (__bf16)(acc0[f][3] * ri0));
    *(ushort4*)&Op0[f * 16 + g * 4] = o0;
    o1.x = __builtin_bit_cast(unsigned short, (__bf16)(acc1[f][0] * ri1));
    o1.y = __builtin_bit_cast(unsigned short, (__bf16)(acc1[f][1] * ri1));
    o1.z = __builtin_bit_cast(unsigned short, (__bf16)(acc1[f][2] * ri1));
    o1.w = __builtin_bit_cast(unsigned short, (__bf16)(acc1[f][3] * ri1));
    *(ushort4*)&Op1[f * 16 + g * 4] = o1;
  }
}

// ---------------------------------------------------------------------------
extern "C" void kernel_launch(void* const* d_in, const int* in_sizes, int n_in,
                              void* d_out, int out_size, void* d_ws, size_t ws_size,
                              hipStream_t stream) {
  (void)in_sizes; (void)n_in; (void)out_size; (void)ws_size;
  const float* q  = (const float*)d_in[0];
  const float* k  = (const float*)d_in[1];
  const float* v  = (const float*)d_in[2];
  const int*   mask = (const int*)d_in[3];
  const float* Wq = (const float*)d_in[4];
  const float* bq = (const float*)d_in[5];
  const float* Wk = (const float*)d_in[6];
  const float* bk = (const float*)d_in[7];
  const float* Wv = (const float*)d_in[8];
  const float* bv = (const float*)d_in[9];
  const float* Wo = (const float*)d_in[10];
  const float* bo = (const float*)d_in[11];

  char* ws = (char*)d_ws;
  const size_t MB = 1024 * 1024;
  __bf16* qb  = (__bf16*)(ws + 0 * MB);    // 8MB  [4096,1024]
  __bf16* kb  = (__bf16*)(ws + 8 * MB);    // 8MB  (dead after GEMM -> Vt)
  __bf16* vb  = (__bf16*)(ws + 16 * MB);   // 8MB
  __bf16* wqb = (__bf16*)(ws + 24 * MB);   // 2MB
  __bf16* wkb = (__bf16*)(ws + 26 * MB);   // 2MB
  __bf16* wvb = (__bf16*)(ws + 28 * MB);   // 2MB
  __bf16* wob = (__bf16*)(ws + 30 * MB);   // 2MB
  __bf16* Qh  = (__bf16*)(ws + 32 * MB);   // 8MB [B,H,S,D]
  __bf16* Kh  = (__bf16*)(ws + 40 * MB);   // 8MB [B,H,S,D]
  __bf16* Vh  = (__bf16*)(ws + 48 * MB);   // 8MB [B,H,S,D]
  unsigned long long* mwords = (unsigned long long*)(ws + 56 * MB);  // 1MB
  __bf16* Vt = kb;   // kb dead after QKV GEMM
  __bf16* Ob = qb;   // qb dead after QKV GEMM

  cvt_kernel<<<dim3(256, 7), 256, 0, stream>>>(q, k, v, Wq, Wk, Wv, Wo,
                                               qb, kb, vb, wqb, wkb, wvb, wob);
  pack_mask_kernel<<<1024, 256, 0, stream>>>(mask, mwords);
  gemm_bt<<<dim3(8, 32, 3), 256, 0, stream>>>(qb, kb, vb, wqb, wkb, wvb,
                                              bq, bk, bv, Qh, Kh, Vh);
  transpose_v_kernel<<<dim3(32, 32), 256, 0, stream>>>(Vh, Vt);
  attn_kernel<<<512, 256, 0, stream>>>(Qh, Kh, Vt, mwords, Ob);
  gemm_out64<<<dim3(16, 32), 256, 0, stream>>>(Ob, wob, bo, (float*)d_out);
}